// Round 1
// baseline (337.353 us; speedup 1.0000x reference)
//
#include <hip/hip_runtime.h>
#include <cstdint>
#include <cstddef>

constexpr int R  = 512;
constexpr int C  = 16;
constexpr int HW = R * R;

// ---------------------------------------------------------------------------
// Transpose one (C,H,W) plane set -> (H,W,C) so each texel's 16 channels are
// a contiguous 64B chunk. Coalesced reads (x-contiguous per channel) and
// coalesced writes via an LDS tile with +1-padded stride (17) to kill bank
// conflicts (17 odd -> all 32 banks cycled).
// grid = (R, R/64, 3), block = 256
// ---------------------------------------------------------------------------
__global__ __launch_bounds__(256) void transpose_chw_hwc(
    const float* __restrict__ p0, const float* __restrict__ p1,
    const float* __restrict__ p2, float* __restrict__ dst)
{
    __shared__ float lds[64 * 17];
    const int y  = blockIdx.x;
    const int x0 = blockIdx.y * 64;
    const int pl = blockIdx.z;
    const float* src = (pl == 0) ? p0 : ((pl == 1) ? p1 : p2);
    const int tid = threadIdx.x;
    const int xl  = tid & 63;   // x within tile
    const int c0  = tid >> 6;   // 0..3
#pragma unroll
    for (int i = 0; i < 4; ++i) {
        const int c = c0 * 4 + i;
        lds[xl * 17 + c] = src[c * HW + y * R + x0 + xl];
    }
    __syncthreads();
    float* dbase = dst + ((size_t)pl * HW + (size_t)(y * R + x0)) * C;
#pragma unroll
    for (int i = 0; i < 4; ++i) {
        const int j = tid + i * 256;        // 0..1023 = x*16 + c
        dbase[j] = lds[(j >> 4) * 17 + (j & 15)];
    }
}

// ---------------------------------------------------------------------------
// Main sampler from (H,W,C) layout. 4 lanes per point, each lane owns a
// float4 channel group. Per plane: 4 corner dwordx4 loads (64B contiguous per
// 4-lane group). Output store lane-contiguous float4 -> 1KB/wave coalesced.
// ---------------------------------------------------------------------------
__global__ __launch_bounds__(256) void sample_hwc(
    const float* __restrict__ x, const float* __restrict__ t,
    float* __restrict__ out, int B)
{
    const int tid = blockIdx.x * 256 + threadIdx.x;
    const int p   = tid >> 2;
    const int cg  = tid & 3;
    if (p >= B) return;

    const float xv0 = x[(size_t)p * 3 + 0];
    const float xv1 = x[(size_t)p * 3 + 1];
    const float xv2 = x[(size_t)p * 3 + 2];

    // PLANE_DIMIDS = [(0,1),(0,2),(1,2)]; gx = x[:,d0] (width), gy = x[:,d1] (height)
    const float gxs[3] = { xv0, xv0, xv1 };
    const float gys[3] = { xv1, xv2, xv2 };

    float4 acc = make_float4(1.f, 1.f, 1.f, 1.f);

#pragma unroll
    for (int pl = 0; pl < 3; ++pl) {
        const float gx = gxs[pl], gy = gys[pl];
        // exact op order as reference: (g + 1) * 0.5 * (R-1)
        const float px = (gx + 1.0f) * 0.5f * (float)(R - 1);
        const float py = (gy + 1.0f) * 0.5f * (float)(R - 1);
        const float x0f = floorf(px), y0f = floorf(py);
        const float wx = px - x0f,   wy = py - y0f;
        int x0 = (int)x0f; x0 = min(max(x0, 0), R - 1);
        int y0 = (int)y0f; y0 = min(max(y0, 0), R - 1);
        const int x1 = min(x0 + 1, R - 1);
        const int y1 = min(y0 + 1, R - 1);

        const float* pb = t + (size_t)pl * (size_t)(HW * C) + cg * 4;
        const float4 p00 = *(const float4*)(pb + (size_t)(y0 * R + x0) * C);
        const float4 p01 = *(const float4*)(pb + (size_t)(y0 * R + x1) * C);
        const float4 p10 = *(const float4*)(pb + (size_t)(y1 * R + x0) * C);
        const float4 p11 = *(const float4*)(pb + (size_t)(y1 * R + x1) * C);

        const float w00 = (1.f - wx) * (1.f - wy);
        const float w01 = wx * (1.f - wy);
        const float w10 = (1.f - wx) * wy;
        const float w11 = wx * wy;

        float4 f;
        f.x = p00.x * w00 + p01.x * w01 + p10.x * w10 + p11.x * w11;
        f.y = p00.y * w00 + p01.y * w01 + p10.y * w10 + p11.y * w11;
        f.z = p00.z * w00 + p01.z * w01 + p10.z * w10 + p11.z * w11;
        f.w = p00.w * w00 + p01.w * w01 + p10.w * w10 + p11.w * w11;

        acc.x *= f.x; acc.y *= f.y; acc.z *= f.z; acc.w *= f.w;
    }

    *(float4*)(out + (size_t)p * C + cg * 4) = acc;
}

// ---------------------------------------------------------------------------
// Fallback if workspace is too small for the transposed planes: gather
// straight from (C,H,W). Correct but slow (kept only as a safety net).
// ---------------------------------------------------------------------------
__global__ __launch_bounds__(256) void sample_chw(
    const float* __restrict__ x,
    const float* __restrict__ p0, const float* __restrict__ p1,
    const float* __restrict__ p2, float* __restrict__ out, int B)
{
    const int tid = blockIdx.x * 256 + threadIdx.x;
    const int p   = tid >> 2;
    const int cg  = tid & 3;
    if (p >= B) return;

    const float xv0 = x[(size_t)p * 3 + 0];
    const float xv1 = x[(size_t)p * 3 + 1];
    const float xv2 = x[(size_t)p * 3 + 2];
    const float gxs[3] = { xv0, xv0, xv1 };
    const float gys[3] = { xv1, xv2, xv2 };
    const float* planes[3] = { p0, p1, p2 };

    float acc[4] = {1.f, 1.f, 1.f, 1.f};

#pragma unroll
    for (int pl = 0; pl < 3; ++pl) {
        const float gx = gxs[pl], gy = gys[pl];
        const float px = (gx + 1.0f) * 0.5f * (float)(R - 1);
        const float py = (gy + 1.0f) * 0.5f * (float)(R - 1);
        const float x0f = floorf(px), y0f = floorf(py);
        const float wx = px - x0f,   wy = py - y0f;
        int x0 = (int)x0f; x0 = min(max(x0, 0), R - 1);
        int y0 = (int)y0f; y0 = min(max(y0, 0), R - 1);
        const int x1 = min(x0 + 1, R - 1);
        const int y1 = min(y0 + 1, R - 1);
        const float w00 = (1.f - wx) * (1.f - wy);
        const float w01 = wx * (1.f - wy);
        const float w10 = (1.f - wx) * wy;
        const float w11 = wx * wy;
        const float* pb = planes[pl];
#pragma unroll
        for (int k = 0; k < 4; ++k) {
            const int c = cg * 4 + k;
            const float* b = pb + (size_t)c * HW;
            const float v00 = b[y0 * R + x0];
            const float v01 = b[y0 * R + x1];
            const float v10 = b[y1 * R + x0];
            const float v11 = b[y1 * R + x1];
            acc[k] *= v00 * w00 + v01 * w01 + v10 * w10 + v11 * w11;
        }
    }

    float* o = out + (size_t)p * C + cg * 4;
    o[0] = acc[0]; o[1] = acc[1]; o[2] = acc[2]; o[3] = acc[3];
}

extern "C" void kernel_launch(void* const* d_in, const int* in_sizes, int n_in,
                              void* d_out, int out_size, void* d_ws, size_t ws_size,
                              hipStream_t stream) {
    const float* x  = (const float*)d_in[0];
    const float* p0 = (const float*)d_in[1];
    const float* p1 = (const float*)d_in[2];
    const float* p2 = (const float*)d_in[3];
    float* out = (float*)d_out;
    const int B = in_sizes[0] / 3;

    const size_t need = (size_t)3 * HW * C * sizeof(float);  // 48 MiB
    const int nthr = B * 4;
    const int nblk = (nthr + 255) / 256;

    if (d_ws != nullptr && ws_size >= need) {
        float* t = (float*)d_ws;
        dim3 tg(R, R / 64, 3);
        transpose_chw_hwc<<<tg, 256, 0, stream>>>(p0, p1, p2, t);
        sample_hwc<<<nblk, 256, 0, stream>>>(x, t, out, B);
    } else {
        sample_chw<<<nblk, 256, 0, stream>>>(x, p0, p1, p2, out, B);
    }
}